// Round 21
// baseline (141.631 us; speedup 1.0000x reference)
//
#include <hip/hip_runtime.h>
#include <hip/hip_bf16.h>
#include <stdint.h>

typedef __bf16 bf16;
typedef __bf16 bf16x8 __attribute__((ext_vector_type(8)));
typedef __bf16 bf16x4 __attribute__((ext_vector_type(4)));
typedef __bf16 bf16x2 __attribute__((ext_vector_type(2)));
typedef float f32x4 __attribute__((ext_vector_type(4)));
typedef float f32x2 __attribute__((ext_vector_type(2)));
typedef int i32x4 __attribute__((ext_vector_type(4)));

#define GAS __attribute__((address_space(1)))
#define LAS __attribute__((address_space(3)))

#define NROIS 1000
#define DEPTH 256
#define CIN 320
#define KDIM 15680      // 490 K-steps of 32
#define TABS 120

// T (bf16) element offsets
#define T_P2 0
#define T_P3 6553600
#define T_P4 8192000
#define T_P5 8601600
#define T_RNG 8704000

// ws layout (aliased; stream-ordered). Max end 99,876,864 <= proven 100,401,152.
//  A [0,32.1M) | Tb [32.1M,+20.7M) | tab [52.8M,+0.5M) | part [32.1M,+33.6M) alias Tb/tab
//  W1b [65.7M,+32.1M) | W2b [97.8M,+2.1M) | x1b [0,2M) alias A | x2 [2.6M,+4M)
#define OFF_A    0ULL
#define OFF_T    32112640ULL
#define OFF_TAB  52797440ULL
#define OFF_PART 32112640ULL
#define OFF_W1   65667072ULL
#define OFF_W2   97779712ULL
#define OFF_X1B  0ULL
#define OFF_X2   2621440ULL

// ---------------- prep: CHW->HWC transpose (bf16) + ROI tables + weight cvt (one grid) -------
__global__ __launch_bounds__(256) void k_prep(const float* __restrict__ p2, const float* __restrict__ p3,
                                              const float* __restrict__ p4, const float* __restrict__ p5,
                                              const float* __restrict__ rng, bf16* __restrict__ Tb,
                                              const float* __restrict__ rois, float* __restrict__ tab,
                                              const float* __restrict__ w1, const float* __restrict__ w2,
                                              bf16* __restrict__ W1b, bf16* __restrict__ W2b) {
    __shared__ float tile[64][65];
    int bid = blockIdx.x, t = threadIdx.x;
    if (bid >= 2532) {   // weight f32->bf16 convert (16704 blocks)
        int idx = (bid - 2532) * 256 + t;
        const int n1 = 16056320 / 4;
        f32x4 v; bf16* dst;
        if (idx < n1) { v = ((const f32x4*)w1)[idx]; dst = W1b + (size_t)idx * 4; }
        else { int k = idx - n1; v = ((const f32x4*)w2)[k]; dst = W2b + (size_t)k * 4; }
        bf16x4 o;
        o[0] = (bf16)v[0]; o[1] = (bf16)v[1]; o[2] = (bf16)v[2]; o[3] = (bf16)v[3];
        *(bf16x4*)dst = o;
        return;
    }
    if (bid >= 2528) {   // roi table blocks
        int n = (bid - 2528) * 256 + t;
        if (n >= NROIS) return;
        float y1 = rois[n*4+0], x1 = rois[n*4+1], y2 = rois[n*4+2], x2 = rois[n*4+3];
        float h = __fsub_rn(y2, y1), w = __fsub_rn(x2, x1);
        float rl = 4.0f + logf(sqrtf(h * w) / (224.0f / 640.0f)) / logf(2.0f);
        int lvl = (int)rintf(rl);
        lvl = min(5, max(2, lvl));
        float* tt = tab + (size_t)n * TABS;
        tt[112] = (float)lvl;
        int Hs0 = 160 >> (lvl - 2);
        for (int g = 0; g < 2; g++) {
            int H = g ? 160 : Hs0;
            float* tg = tt + g * 56;
            float fH = (float)(H - 1);
            float a = __fmul_rn(y1, fH);
            float s = __fdiv_rn(__fmul_rn(h, fH), 6.0f);
            for (int i = 0; i < 7; i++) {
                float iny = __fadd_rn(a, __fmul_rn((float)i, s));
                float tp = floorf(iny), bt = ceilf(iny);
                tg[i]      = (float)min(H-1, max(0, (int)tp));
                tg[7 + i]  = (float)min(H-1, max(0, (int)bt));
                tg[14 + i] = iny - tp;
                tg[21 + i] = (iny >= 0.0f && iny <= fH) ? 1.0f : 0.0f;
            }
            a = __fmul_rn(x1, fH);
            s = __fdiv_rn(__fmul_rn(w, fH), 6.0f);
            for (int j = 0; j < 7; j++) {
                float inx = __fadd_rn(a, __fmul_rn((float)j, s));
                float lf = floorf(inx), rt = ceilf(inx);
                tg[28 + j] = (float)min(H-1, max(0, (int)lf));
                tg[35 + j] = (float)min(H-1, max(0, (int)rt));
                tg[42 + j] = inx - lf;
                tg[49 + j] = (inx >= 0.0f && inx <= fH) ? 1.0f : 0.0f;
            }
        }
        return;
    }
    const float* src; bf16* dst; int C, X, loc;
    if (bid < 1600)      { src = p2;  dst = Tb + T_P2;  C = 256; X = 25600; loc = bid; }
    else if (bid < 2000) { src = p3;  dst = Tb + T_P3;  C = 256; X = 6400;  loc = bid - 1600; }
    else if (bid < 2100) { src = p4;  dst = Tb + T_P4;  C = 256; X = 1600;  loc = bid - 2000; }
    else if (bid < 2128) { src = p5;  dst = Tb + T_P5;  C = 256; X = 400;   loc = bid - 2100; }
    else                 { src = rng; dst = Tb + T_RNG; C = 64;  X = 25600; loc = bid - 2128; }
    int xtiles = (X + 63) >> 6;
    int xt = loc % xtiles, ct = loc / xtiles;
    int x0 = xt << 6, c0 = ct << 6;
    #pragma unroll
    for (int r = 0; r < 4; r++) {
        int e4 = r * 256 + t;
        int lc = e4 >> 4;
        int lx4 = (e4 & 15) << 2;
        int x = x0 + lx4;
        f32x4 v = {};
        if (x < X) v = *(const f32x4*)(src + (size_t)(c0 + lc) * X + x);
        tile[lc][lx4]     = v[0];
        tile[lc][lx4 + 1] = v[1];
        tile[lc][lx4 + 2] = v[2];
        tile[lc][lx4 + 3] = v[3];
    }
    __syncthreads();
    #pragma unroll
    for (int r = 0; r < 2; r++) {
        int lp = r * 256 + t;
        int lxx = lp >> 3;
        int lc8 = (lp & 7) * 8;
        int x = x0 + lxx;
        if (x < X) {
            bf16x8 o;
            #pragma unroll
            for (int k = 0; k < 8; k++) o[k] = (bf16)tile[lc8 + k][lxx];
            *(bf16x8*)(dst + (size_t)x * C + c0 + lc8) = o;
        }
    }
}

// ---------------- crop_and_resize from bf16 NHWC: chunked LDS (R13-proven) ----------
#define RES_S 134
__global__ __launch_bounds__(256) void k_crop2(const bf16* __restrict__ Tb, const float* __restrict__ tab,
                                               float* __restrict__ out_rf, bf16* __restrict__ A) {
    int n = blockIdx.x, t = threadIdx.x;
    if (n >= NROIS) {                 // zero-pad A rows 1000..1023
        i32x4* row = (i32x4*)(A + (size_t)n * KDIM);
        for (int i = t; i < KDIM * 2 / 16; i += 256) row[i] = i32x4{0,0,0,0};
        return;
    }
    __shared__ float res[49 * RES_S];
    __shared__ float tl_[TABS];
    if (t < TABS) tl_[t] = tab[(size_t)n * TABS + t];
    __syncthreads();
    int lvl = (int)tl_[112];
    int H = 160 >> (lvl - 2);
    int toff = (lvl == 2) ? T_P2 : (lvl == 3) ? T_P3 : (lvl == 4) ? T_P4 : T_P5;
    const bf16* F = Tb + toff;
    const bf16* R = Tb + T_RNG;
    size_t ob = (size_t)n * KDIM;

#define CVT4(d_, s_) f32x4 d_; { bf16x4 b_ = s_; d_[0] = (float)b_[0]; d_[1] = (float)b_[1]; d_[2] = (float)b_[2]; d_[3] = (float)b_[3]; }

    for (int ch = 0; ch < 3; ch++) {
        if (ch < 2) {
            int q = t & 31, pl = t >> 5;
            int c4 = ch * 128 + q * 4;
            #pragma unroll
            for (int g = 0; g < 7; g++) {
                int pos = g * 8 + pl;
                if (pos < 49) {
                    int i = pos / 7, j = pos % 7;
                    int ti = (int)tl_[i],      bi = (int)tl_[7 + i];
                    int li = (int)tl_[28 + j], ri = (int)tl_[35 + j];
                    float ly = tl_[14 + i], lx = tl_[42 + j];
                    float valid = tl_[21 + i] * tl_[49 + j];
                    CVT4(vtl, *(const bf16x4*)(F + (size_t)(ti * H + li) * 256 + c4));
                    CVT4(vtr, *(const bf16x4*)(F + (size_t)(ti * H + ri) * 256 + c4));
                    CVT4(vbl, *(const bf16x4*)(F + (size_t)(bi * H + li) * 256 + c4));
                    CVT4(vbr, *(const bf16x4*)(F + (size_t)(bi * H + ri) * 256 + c4));
                    f32x4 top = vtl + (vtr - vtl) * lx;
                    f32x4 bot = vbl + (vbr - vbl) * lx;
                    f32x4 v = top + (bot - top) * ly;
                    if (valid == 0.0f) v = f32x4{0.f,0.f,0.f,0.f};
                    *(f32x2*)(&res[pos * RES_S + q * 4])     = f32x2{v[0], v[1]};
                    *(f32x2*)(&res[pos * RES_S + q * 4 + 2]) = f32x2{v[2], v[3]};
                }
            }
        } else {
            int q = t & 15, pl = t >> 4;
            int c4 = q * 4;
            #pragma unroll
            for (int g = 0; g < 4; g++) {
                int pos = g * 16 + pl;
                if (pos < 49) {
                    int i = pos / 7, j = pos % 7;
                    int ti = (int)tl_[56 + i], bi = (int)tl_[63 + i];
                    int li = (int)tl_[84 + j], ri = (int)tl_[91 + j];
                    float ly = tl_[70 + i], lx = tl_[98 + j];
                    float valid = tl_[77 + i] * tl_[105 + j];
                    CVT4(vtl, *(const bf16x4*)(R + (size_t)(ti * 160 + li) * 64 + c4));
                    CVT4(vtr, *(const bf16x4*)(R + (size_t)(ti * 160 + ri) * 64 + c4));
                    CVT4(vbl, *(const bf16x4*)(R + (size_t)(bi * 160 + li) * 64 + c4));
                    CVT4(vbr, *(const bf16x4*)(R + (size_t)(bi * 160 + ri) * 64 + c4));
                    f32x4 top = vtl + (vtr - vtl) * lx;
                    f32x4 bot = vbl + (vbr - vbl) * lx;
                    f32x4 v = top + (bot - top) * ly;
                    if (valid == 0.0f) v = f32x4{0.f,0.f,0.f,0.f};
                    *(f32x2*)(&res[pos * RES_S + q * 4])     = f32x2{v[0], v[1]};
                    *(f32x2*)(&res[pos * RES_S + q * 4 + 2]) = f32x2{v[2], v[3]};
                }
            }
        }
        __syncthreads();
        int E = ((ch == 2) ? 64 : 128) * 49;
        int base = ch * 128 * 49;
        for (int k4 = 0; k4 * 1024 < E; k4++) {
            int off = (k4 * 256 + t) * 4;
            if (off < E) {
                f32x4 vo; bf16x4 bo;
                #pragma unroll
                for (int e = 0; e < 4; e++) {
                    int idx = off + e;
                    int c = idx / 49;
                    int pos = idx - c * 49;
                    float val = res[pos * RES_S + c];
                    vo[e] = val; bo[e] = (bf16)val;
                }
                *(f32x4*)(out_rf + ob + base + off) = vo;
                *(bf16x4*)(A + ob + base + off) = bo;
            }
        }
        __syncthreads();
    }
#undef CVT4
}

// ---------------- 128x128 GEMM, BK=32: 32KB LDS -> 4 blocks/CU; counted vmcnt; swizzle ------
// LDS [128 rows][32 cols bf16] per operand per buf; slot s at row r holds source cols
// (s ^ ((r>>1)&3))*8 -> ds_read 16B slices hit 8 distinct 16B-slots per 8 rows (2-way, free).
// REMAP: z=16, 1024 blocks, bz = xcd + 8*(slot>>6) -> K-sharers co-located per XCD.
template<int REMAP>
__global__ __launch_bounds__(256)
void k_g32(const bf16* __restrict__ A, const bf16* __restrict__ B,
           bf16* __restrict__ part, const int K, const int steps_base, const int steps_rem) {
    __shared__ bf16 sA[2][4096];   // [buf][128*32]
    __shared__ bf16 sB[2][4096];
    int tid = threadIdx.x;
    int l = tid & 63, w = tid >> 6;
    int bx, by, bz;
    if (REMAP) {
        int id = blockIdx.x;
        int xcd = id & 7, slot = id >> 3;          // slot in [0,128)
        bx = slot & 7; by = (slot >> 3) & 7;
        bz = xcd + 8 * (slot >> 6);
    } else { bx = blockIdx.x; by = blockIdx.y; bz = blockIdx.z; }
    int tm = bx * 128, tn = by * 128;
    int s0 = bz * steps_base + min(bz, steps_rem);
    int ns = steps_base + (bz < steps_rem ? 1 : 0);
    int kend = s0 + ns;

    // staging: thread -> (row = tid>>2 and +64, slot = tid&3); source col pre-swizzled
    int srow = tid >> 2, sslot = tid & 3;
    int scol = (sslot ^ ((srow >> 1) & 3)) << 3;   // same for srow and srow+64
    const bf16* Asrc = A + (size_t)(tm + srow) * K + scol;
    const bf16* Bsrc = B + (size_t)(tn + srow) * K + scol;
    int d0 = srow * 32 + sslot * 8;
    int d1 = (srow + 64) * 32 + sslot * 8;

    int lr = l & 15, lh = l >> 4;
    int sxor = (lr >> 1) & 3;
    int wm = (w >> 1) * 64, wn = (w & 1) * 64;

    f32x4 acc[4][4] = {};

#define STAGE(pb_, t_) do { int kc_ = (t_) * 32; \
    __builtin_amdgcn_global_load_lds((const GAS void*)(Asrc + kc_), (LAS void*)(&sA[pb_][d0]), 16, 0, 0); \
    __builtin_amdgcn_global_load_lds((const GAS void*)(Asrc + (size_t)64 * K + kc_), (LAS void*)(&sA[pb_][d1]), 16, 0, 0); \
    __builtin_amdgcn_global_load_lds((const GAS void*)(Bsrc + kc_), (LAS void*)(&sB[pb_][d0]), 16, 0, 0); \
    __builtin_amdgcn_global_load_lds((const GAS void*)(Bsrc + (size_t)64 * K + kc_), (LAS void*)(&sB[pb_][d1]), 16, 0, 0); \
} while (0)

    STAGE(0, s0);
    int p = 0;
    for (int t = s0; t < kend; t++) {
        if (t + 1 < kend) {
            STAGE(p ^ 1, t + 1);
            asm volatile("s_waitcnt vmcnt(4)" ::: "memory");   // buf p ready; prefetch in flight
        } else {
            asm volatile("s_waitcnt vmcnt(0)" ::: "memory");
        }
        __builtin_amdgcn_s_barrier();
        __builtin_amdgcn_sched_barrier(0);
        {
            int so = (lh ^ sxor) << 3;
            bf16x8 af[4], bfr[4];
            #pragma unroll
            for (int mi = 0; mi < 4; mi++)
                af[mi] = *(const bf16x8*)(&sA[p][(wm + mi * 16 + lr) * 32 + so]);
            #pragma unroll
            for (int ni = 0; ni < 4; ni++)
                bfr[ni] = *(const bf16x8*)(&sB[p][(wn + ni * 16 + lr) * 32 + so]);
            __builtin_amdgcn_s_setprio(1);
            #pragma unroll
            for (int mi = 0; mi < 4; mi++)
                #pragma unroll
                for (int ni = 0; ni < 4; ni++)
                    acc[mi][ni] = __builtin_amdgcn_mfma_f32_16x16x32_bf16(af[mi], bfr[ni], acc[mi][ni], 0, 0, 0);
            __builtin_amdgcn_s_setprio(0);
        }
        __builtin_amdgcn_sched_barrier(0);
        asm volatile("s_waitcnt lgkmcnt(0)" ::: "memory");
        __builtin_amdgcn_s_barrier();
        p ^= 1;
    }
#undef STAGE
    bf16* pc = part + ((size_t)bz << 20);
    #pragma unroll
    for (int mi = 0; mi < 4; mi++)
        #pragma unroll
        for (int ni = 0; ni < 4; ni++)
            #pragma unroll
            for (int r = 0; r < 4; r++)
                pc[(size_t)(tm + wm + mi * 16 + lh * 4 + r) * 1024 + (tn + wn + ni * 16 + lr)] = (bf16)acc[mi][ni][r];
}

// ---------------- reduce split-K(16, bf16 partials) + bias + BN + ReLU -> bf16 (x1) --------
__global__ void k_reduce1(const bf16* __restrict__ part, const float* __restrict__ bias,
                          const float* __restrict__ gam, const float* __restrict__ bet,
                          const float* __restrict__ mu, const float* __restrict__ var,
                          bf16* __restrict__ x1b) {
    int idx = blockIdx.x * 256 + threadIdx.x;
    int n = idx >> 8;
    int o = (idx & 255) << 2;
    f32x4 v = {};
    #pragma unroll
    for (int s = 0; s < 16; s++) {
        bf16x4 p4 = *(const bf16x4*)(part + ((size_t)s << 20) + (size_t)n * 1024 + o);
        #pragma unroll
        for (int e = 0; e < 4; e++) v[e] += (float)p4[e];
    }
    f32x4 b4 = *(const f32x4*)(bias + o);
    f32x4 g4 = *(const f32x4*)(gam + o);
    f32x4 e4 = *(const f32x4*)(bet + o);
    f32x4 m4 = *(const f32x4*)(mu + o);
    f32x4 v4 = *(const f32x4*)(var + o);
    bf16x4 ov;
    #pragma unroll
    for (int e = 0; e < 4; e++) {
        float sc = g4[e] / sqrtf(v4[e] + 0.001f);
        float y = (v[e] + b4[e] - m4[e]) * sc + e4[e];
        y = fmaxf(y, 0.0f);
        if (n >= NROIS) y = 0.0f;
        ov[e] = (bf16)y;
    }
    *(bf16x4*)(x1b + (size_t)n * 1024 + o) = ov;
}

// ---------------- reduce split-K(8, bf16 partials) + bias + BN + ReLU -> f32 (x2) ----------
__global__ void k_reduce2(const bf16* __restrict__ part, const float* __restrict__ bias,
                          const float* __restrict__ gam, const float* __restrict__ bet,
                          const float* __restrict__ mu, const float* __restrict__ var,
                          float* __restrict__ x2) {
    int idx = blockIdx.x * 256 + threadIdx.x;
    int n = idx >> 8;
    int o = (idx & 255) << 2;
    f32x4 v = {};
    #pragma unroll
    for (int s = 0; s < 8; s++) {
        bf16x4 p4 = *(const bf16x4*)(part + ((size_t)s << 20) + (size_t)n * 1024 + o);
        #pragma unroll
        for (int e = 0; e < 4; e++) v[e] += (float)p4[e];
    }
    f32x4 b4 = *(const f32x4*)(bias + o);
    f32x4 g4 = *(const f32x4*)(gam + o);
    f32x4 e4 = *(const f32x4*)(bet + o);
    f32x4 m4 = *(const f32x4*)(mu + o);
    f32x4 v4 = *(const f32x4*)(var + o);
    f32x4 ov;
    #pragma unroll
    for (int e = 0; e < 4; e++) {
        float sc = g4[e] / sqrtf(v4[e] + 0.001f);
        float y = (v[e] + b4[e] - m4[e]) * sc + e4[e];
        ov[e] = fmaxf(y, 0.0f);
    }
    *(f32x4*)(x2 + (size_t)n * 1024 + o) = ov;
}

// ---------------- heads ----------------
__device__ __forceinline__ float wred(float v) {
    #pragma unroll
    for (int off = 32; off; off >>= 1) v += __shfl_xor(v, off);
    return v;
}

__global__ void k_heads(const float* __restrict__ x2,
                        const float* __restrict__ wc, const float* __restrict__ bc,
                        const float* __restrict__ wb, const float* __restrict__ bb,
                        const float* __restrict__ wp, const float* __restrict__ bp,
                        float* __restrict__ out) {
    int w = threadIdx.x >> 6, l = threadIdx.x & 63;
    int n = blockIdx.x * 4 + w;
    float ac0 = 0.f, ac1 = 0.f, ab[8] = {}, ap[6] = {};
    const float* xr = x2 + (size_t)n * 1024;
    for (int kk = 0; kk < 16; kk++) {
        int k = kk * 64 + l;
        float xv = xr[k];
        ac0 += xv * wc[k];
        ac1 += xv * wc[1024 + k];
        #pragma unroll
        for (int o = 0; o < 8; o++) ab[o] += xv * wb[o * 1024 + k];
        #pragma unroll
        for (int o = 0; o < 6; o++) ap[o] += xv * wp[o * 1024 + k];
    }
    ac0 = wred(ac0); ac1 = wred(ac1);
    #pragma unroll
    for (int o = 0; o < 8; o++) ab[o] = wred(ab[o]);
    #pragma unroll
    for (int o = 0; o < 6; o++) ap[o] = wred(ap[o]);
    if (l == 0) {
        float l0 = ac0 + bc[0], l1 = ac1 + bc[1];
        out[n * 2] = l0; out[n * 2 + 1] = l1;
        float m = fmaxf(l0, l1);
        float e0 = expf(l0 - m), e1 = expf(l1 - m);
        float inv = 1.0f / (e0 + e1);
        out[2000 + n * 2] = e0 * inv; out[2000 + n * 2 + 1] = e1 * inv;
        #pragma unroll
        for (int o = 0; o < 8; o++) out[4000 + n * 8 + o] = ab[o] + bb[o];
        #pragma unroll
        for (int o = 0; o < 6; o++) out[12000 + n * 6 + o] = ap[o] + bp[o];
    }
}

extern "C" void kernel_launch(void* const* d_in, const int* in_sizes, int n_in,
                              void* d_out, int out_size, void* d_ws, size_t ws_size,
                              hipStream_t stream) {
    const float* p2      = (const float*)d_in[0];
    const float* p3      = (const float*)d_in[1];
    const float* p4      = (const float*)d_in[2];
    const float* p5      = (const float*)d_in[3];
    const float* rois    = (const float*)d_in[4];
    const float* ranges  = (const float*)d_in[5];
    const float* conv1_w = (const float*)d_in[6];
    const float* conv1_b = (const float*)d_in[7];
    const float* bn1_g   = (const float*)d_in[8];
    const float* bn1_b   = (const float*)d_in[9];
    const float* bn1_m   = (const float*)d_in[10];
    const float* bn1_v   = (const float*)d_in[11];
    const float* conv2_w = (const float*)d_in[12];
    const float* conv2_b = (const float*)d_in[13];
    const float* bn2_g   = (const float*)d_in[14];
    const float* bn2_b   = (const float*)d_in[15];
    const float* bn2_m   = (const float*)d_in[16];
    const float* bn2_v   = (const float*)d_in[17];
    const float* wc      = (const float*)d_in[18];
    const float* bc      = (const float*)d_in[19];
    const float* wb      = (const float*)d_in[20];
    const float* bb      = (const float*)d_in[21];
    const float* wp      = (const float*)d_in[22];
    const float* bp      = (const float*)d_in[23];

    char* ws = (char*)d_ws;
    bf16*  A    = (bf16*)(ws + OFF_A);
    bf16*  Tb   = (bf16*)(ws + OFF_T);
    float* tab  = (float*)(ws + OFF_TAB);
    bf16*  part = (bf16*)(ws + OFF_PART);
    bf16*  W1b  = (bf16*)(ws + OFF_W1);
    bf16*  W2b  = (bf16*)(ws + OFF_W2);
    bf16*  x1b  = (bf16*)(ws + OFF_X1B);
    float* x2   = (float*)(ws + OFF_X2);
    float* out  = (float*)d_out;

    // prep: transpose (2528) + roi tables (4) + weight convert (16704) = 19236 blocks
    k_prep<<<19236, 256, 0, stream>>>(p2, p3, p4, p5, ranges, Tb, rois, tab,
                                      conv1_w, conv2_w, W1b, W2b);
    k_crop2<<<1024, 256, 0, stream>>>(Tb, tab, out + 18000, A);
    // GEMM1: M=N=1024, K=15680 (490 steps of 32), z=16 (490 = 16*30+10), 1024 blocks (4/CU)
    k_g32<1><<<1024, 256, 0, stream>>>(A, W1b, part, KDIM, 30, 10);
    k_reduce1<<<1024, 256, 0, stream>>>(part, conv1_b, bn1_g, bn1_b, bn1_m, bn1_v, x1b);
    // GEMM2: K=1024 (32 steps of 32), z=8 -> 512 blocks, 4 steps each
    k_g32<0><<<dim3(8, 8, 8), 256, 0, stream>>>(x1b, W2b, part, 1024, 4, 0);
    k_reduce2<<<1024, 256, 0, stream>>>(part, conv2_b, bn2_g, bn2_b, bn2_m, bn2_v, x2);
    k_heads<<<250, 256, 0, stream>>>(x2, wc, bc, wb, bb, wp, bp, out);
}

// Round 22
// 126.774 us; speedup vs baseline: 1.1172x; 1.1172x over previous
//
#include <hip/hip_runtime.h>
#include <hip/hip_bf16.h>
#include <stdint.h>

typedef __bf16 bf16;
typedef __bf16 bf16x8 __attribute__((ext_vector_type(8)));
typedef __bf16 bf16x4 __attribute__((ext_vector_type(4)));
typedef __bf16 bf16x2 __attribute__((ext_vector_type(2)));
typedef float f32x4 __attribute__((ext_vector_type(4)));
typedef float f32x2 __attribute__((ext_vector_type(2)));
typedef int i32x4 __attribute__((ext_vector_type(4)));

#define GAS __attribute__((address_space(1)))
#define LAS __attribute__((address_space(3)))

#define NROIS 1000
#define DEPTH 256
#define CIN 320
#define KDIM 15680      // 245 K-tiles of 64
#define TABS 120

// T (bf16) element offsets
#define T_P2 0
#define T_P3 6553600
#define T_P4 8192000
#define T_P5 8601600
#define T_RNG 8704000

// ws layout (aliased; stream-ordered). Max end 99,876,864 <= proven 100,401,152.
#define OFF_A    0ULL
#define OFF_T    32112640ULL
#define OFF_TAB  52797440ULL
#define OFF_PART 32112640ULL
#define OFF_W1   65667072ULL
#define OFF_W2   97779712ULL
#define OFF_X1B  0ULL

// ---------------- prep: CHW->HWC transpose (bf16) + ROI tables + weight cvt (one grid) -------
__global__ __launch_bounds__(256) void k_prep(const float* __restrict__ p2, const float* __restrict__ p3,
                                              const float* __restrict__ p4, const float* __restrict__ p5,
                                              const float* __restrict__ rng, bf16* __restrict__ Tb,
                                              const float* __restrict__ rois, float* __restrict__ tab,
                                              const float* __restrict__ w1, const float* __restrict__ w2,
                                              bf16* __restrict__ W1b, bf16* __restrict__ W2b) {
    __shared__ float tile[64][65];
    int bid = blockIdx.x, t = threadIdx.x;
    if (bid >= 2532) {   // weight f32->bf16 convert (16704 blocks)
        int idx = (bid - 2532) * 256 + t;
        const int n1 = 16056320 / 4;
        f32x4 v; bf16* dst;
        if (idx < n1) { v = ((const f32x4*)w1)[idx]; dst = W1b + (size_t)idx * 4; }
        else { int k = idx - n1; v = ((const f32x4*)w2)[k]; dst = W2b + (size_t)k * 4; }
        bf16x4 o;
        o[0] = (bf16)v[0]; o[1] = (bf16)v[1]; o[2] = (bf16)v[2]; o[3] = (bf16)v[3];
        *(bf16x4*)dst = o;
        return;
    }
    if (bid >= 2528) {   // roi table blocks
        int n = (bid - 2528) * 256 + t;
        if (n >= NROIS) return;
        float y1 = rois[n*4+0], x1 = rois[n*4+1], y2 = rois[n*4+2], x2 = rois[n*4+3];
        float h = __fsub_rn(y2, y1), w = __fsub_rn(x2, x1);
        float rl = 4.0f + logf(sqrtf(h * w) / (224.0f / 640.0f)) / logf(2.0f);
        int lvl = (int)rintf(rl);
        lvl = min(5, max(2, lvl));
        float* tt = tab + (size_t)n * TABS;
        tt[112] = (float)lvl;
        int Hs0 = 160 >> (lvl - 2);
        for (int g = 0; g < 2; g++) {
            int H = g ? 160 : Hs0;
            float* tg = tt + g * 56;
            float fH = (float)(H - 1);
            float a = __fmul_rn(y1, fH);
            float s = __fdiv_rn(__fmul_rn(h, fH), 6.0f);
            for (int i = 0; i < 7; i++) {
                float iny = __fadd_rn(a, __fmul_rn((float)i, s));
                float tp = floorf(iny), bt = ceilf(iny);
                tg[i]      = (float)min(H-1, max(0, (int)tp));
                tg[7 + i]  = (float)min(H-1, max(0, (int)bt));
                tg[14 + i] = iny - tp;
                tg[21 + i] = (iny >= 0.0f && iny <= fH) ? 1.0f : 0.0f;
            }
            a = __fmul_rn(x1, fH);
            s = __fdiv_rn(__fmul_rn(w, fH), 6.0f);
            for (int j = 0; j < 7; j++) {
                float inx = __fadd_rn(a, __fmul_rn((float)j, s));
                float lf = floorf(inx), rt = ceilf(inx);
                tg[28 + j] = (float)min(H-1, max(0, (int)lf));
                tg[35 + j] = (float)min(H-1, max(0, (int)rt));
                tg[42 + j] = inx - lf;
                tg[49 + j] = (inx >= 0.0f && inx <= fH) ? 1.0f : 0.0f;
            }
        }
        return;
    }
    const float* src; bf16* dst; int C, X, loc;
    if (bid < 1600)      { src = p2;  dst = Tb + T_P2;  C = 256; X = 25600; loc = bid; }
    else if (bid < 2000) { src = p3;  dst = Tb + T_P3;  C = 256; X = 6400;  loc = bid - 1600; }
    else if (bid < 2100) { src = p4;  dst = Tb + T_P4;  C = 256; X = 1600;  loc = bid - 2000; }
    else if (bid < 2128) { src = p5;  dst = Tb + T_P5;  C = 256; X = 400;   loc = bid - 2100; }
    else                 { src = rng; dst = Tb + T_RNG; C = 64;  X = 25600; loc = bid - 2128; }
    int xtiles = (X + 63) >> 6;
    int xt = loc % xtiles, ct = loc / xtiles;
    int x0 = xt << 6, c0 = ct << 6;
    // load phase: f32x4 per request (R19-proven)
    #pragma unroll
    for (int r = 0; r < 4; r++) {
        int e4 = r * 256 + t;
        int lc = e4 >> 4;
        int lx4 = (e4 & 15) << 2;
        int x = x0 + lx4;
        f32x4 v = {};
        if (x < X) v = *(const f32x4*)(src + (size_t)(c0 + lc) * X + x);
        tile[lc][lx4]     = v[0];
        tile[lc][lx4 + 1] = v[1];
        tile[lc][lx4 + 2] = v[2];
        tile[lc][lx4 + 3] = v[3];
    }
    __syncthreads();
    // write phase: bf16x8 (16B) per request (R20-proven)
    #pragma unroll
    for (int r = 0; r < 2; r++) {
        int lp = r * 256 + t;
        int lxx = lp >> 3;
        int lc8 = (lp & 7) * 8;
        int x = x0 + lxx;
        if (x < X) {
            bf16x8 o;
            #pragma unroll
            for (int k = 0; k < 8; k++) o[k] = (bf16)tile[lc8 + k][lxx];
            *(bf16x8*)(dst + (size_t)x * C + c0 + lc8) = o;
        }
    }
}

// ---------------- crop_and_resize from bf16 NHWC: chunked LDS (R13-proven) ----------
#define RES_S 134
__global__ __launch_bounds__(256) void k_crop2(const bf16* __restrict__ Tb, const float* __restrict__ tab,
                                               float* __restrict__ out_rf, bf16* __restrict__ A) {
    int n = blockIdx.x, t = threadIdx.x;
    if (n >= NROIS) {                 // zero-pad A rows 1000..1023
        i32x4* row = (i32x4*)(A + (size_t)n * KDIM);
        for (int i = t; i < KDIM * 2 / 16; i += 256) row[i] = i32x4{0,0,0,0};
        return;
    }
    __shared__ float res[49 * RES_S];
    __shared__ float tl_[TABS];
    if (t < TABS) tl_[t] = tab[(size_t)n * TABS + t];
    __syncthreads();
    int lvl = (int)tl_[112];
    int H = 160 >> (lvl - 2);
    int toff = (lvl == 2) ? T_P2 : (lvl == 3) ? T_P3 : (lvl == 4) ? T_P4 : T_P5;
    const bf16* F = Tb + toff;
    const bf16* R = Tb + T_RNG;
    size_t ob = (size_t)n * KDIM;

#define CVT4(d_, s_) f32x4 d_; { bf16x4 b_ = s_; d_[0] = (float)b_[0]; d_[1] = (float)b_[1]; d_[2] = (float)b_[2]; d_[3] = (float)b_[3]; }

    for (int ch = 0; ch < 3; ch++) {
        if (ch < 2) {
            int q = t & 31, pl = t >> 5;
            int c4 = ch * 128 + q * 4;
            #pragma unroll
            for (int g = 0; g < 7; g++) {
                int pos = g * 8 + pl;
                if (pos < 49) {
                    int i = pos / 7, j = pos % 7;
                    int ti = (int)tl_[i],      bi = (int)tl_[7 + i];
                    int li = (int)tl_[28 + j], ri = (int)tl_[35 + j];
                    float ly = tl_[14 + i], lx = tl_[42 + j];
                    float valid = tl_[21 + i] * tl_[49 + j];
                    CVT4(vtl, *(const bf16x4*)(F + (size_t)(ti * H + li) * 256 + c4));
                    CVT4(vtr, *(const bf16x4*)(F + (size_t)(ti * H + ri) * 256 + c4));
                    CVT4(vbl, *(const bf16x4*)(F + (size_t)(bi * H + li) * 256 + c4));
                    CVT4(vbr, *(const bf16x4*)(F + (size_t)(bi * H + ri) * 256 + c4));
                    f32x4 top = vtl + (vtr - vtl) * lx;
                    f32x4 bot = vbl + (vbr - vbl) * lx;
                    f32x4 v = top + (bot - top) * ly;
                    if (valid == 0.0f) v = f32x4{0.f,0.f,0.f,0.f};
                    *(f32x2*)(&res[pos * RES_S + q * 4])     = f32x2{v[0], v[1]};
                    *(f32x2*)(&res[pos * RES_S + q * 4 + 2]) = f32x2{v[2], v[3]};
                }
            }
        } else {
            int q = t & 15, pl = t >> 4;
            int c4 = q * 4;
            #pragma unroll
            for (int g = 0; g < 4; g++) {
                int pos = g * 16 + pl;
                if (pos < 49) {
                    int i = pos / 7, j = pos % 7;
                    int ti = (int)tl_[56 + i], bi = (int)tl_[63 + i];
                    int li = (int)tl_[84 + j], ri = (int)tl_[91 + j];
                    float ly = tl_[70 + i], lx = tl_[98 + j];
                    float valid = tl_[77 + i] * tl_[105 + j];
                    CVT4(vtl, *(const bf16x4*)(R + (size_t)(ti * 160 + li) * 64 + c4));
                    CVT4(vtr, *(const bf16x4*)(R + (size_t)(ti * 160 + ri) * 64 + c4));
                    CVT4(vbl, *(const bf16x4*)(R + (size_t)(bi * 160 + li) * 64 + c4));
                    CVT4(vbr, *(const bf16x4*)(R + (size_t)(bi * 160 + ri) * 64 + c4));
                    f32x4 top = vtl + (vtr - vtl) * lx;
                    f32x4 bot = vbl + (vbr - vbl) * lx;
                    f32x4 v = top + (bot - top) * ly;
                    if (valid == 0.0f) v = f32x4{0.f,0.f,0.f,0.f};
                    *(f32x2*)(&res[pos * RES_S + q * 4])     = f32x2{v[0], v[1]};
                    *(f32x2*)(&res[pos * RES_S + q * 4 + 2]) = f32x2{v[2], v[3]};
                }
            }
        }
        __syncthreads();
        int E = ((ch == 2) ? 64 : 128) * 49;
        int base = ch * 128 * 49;
        for (int k4 = 0; k4 * 1024 < E; k4++) {
            int off = (k4 * 256 + t) * 4;
            if (off < E) {
                f32x4 vo; bf16x4 bo;
                #pragma unroll
                for (int e = 0; e < 4; e++) {
                    int idx = off + e;
                    int c = idx / 49;
                    int pos = idx - c * 49;
                    float val = res[pos * RES_S + c];
                    vo[e] = val; bo[e] = (bf16)val;
                }
                *(f32x4*)(out_rf + ob + base + off) = vo;
                *(bf16x4*)(A + ob + base + off) = bo;
            }
        }
        __syncthreads();
    }
#undef CVT4
}

// ---------------- 128x128 GEMM (R20-proven): dbuf DMA prefetch + counted vmcnt + swizzle -----
template<int REMAP>
__global__ __launch_bounds__(256)
void k_g128s(const bf16* __restrict__ A, const bf16* __restrict__ B,
             bf16* __restrict__ part, const int K, const int steps_base, const int steps_rem) {
    __shared__ bf16 sA[2][8192];
    __shared__ bf16 sB[2][8192];
    int tid = threadIdx.x;
    int l = tid & 63, w = tid >> 6;
    int bx, by, bz;
    if (REMAP) {
        int id = blockIdx.x;
        int xcd = id & 7, slot = id >> 3;
        bx = slot & 7; by = slot >> 3; bz = xcd;
    } else { bx = blockIdx.x; by = blockIdx.y; bz = blockIdx.z; }
    int tm = bx * 128, tn = by * 128;
    int s0 = bz * steps_base + min(bz, steps_rem);
    int ns = steps_base + (bz < steps_rem ? 1 : 0);
    int kend = s0 + ns;

    int arow = tid >> 3;
    int scol = ((tid & 7) ^ (arow & 7)) << 3;
    const bf16* Asrc = A + (size_t)(tm + arow) * K + scol;
    const bf16* Bsrc = B + (size_t)(tn + arow) * K + scol;

    int lr = l & 15, lh = l >> 4;
    int sxor = lr & 7;
    int wm = (w >> 1) * 64, wn = (w & 1) * 64;

    f32x4 acc[4][4] = {};

#define STAGE(pb_, t_) do { int kc_ = (t_) * 64; \
    _Pragma("unroll") for (int q_ = 0; q_ < 4; q_++) { \
        __builtin_amdgcn_global_load_lds((const GAS void*)(Asrc + (size_t)(q_ * 32) * K + kc_), \
                                         (LAS void*)(&sA[pb_][(q_ * 256 + tid) * 8]), 16, 0, 0); \
        __builtin_amdgcn_global_load_lds((const GAS void*)(Bsrc + (size_t)(q_ * 32) * K + kc_), \
                                         (LAS void*)(&sB[pb_][(q_ * 256 + tid) * 8]), 16, 0, 0); } \
} while (0)

    STAGE(0, s0);
    int p = 0;
    for (int t = s0; t < kend; t++) {
        if (t + 1 < kend) {
            STAGE(p ^ 1, t + 1);
            asm volatile("s_waitcnt vmcnt(8)" ::: "memory");
        } else {
            asm volatile("s_waitcnt vmcnt(0)" ::: "memory");
        }
        __builtin_amdgcn_s_barrier();
        __builtin_amdgcn_sched_barrier(0);
        #pragma unroll
        for (int ks2 = 0; ks2 < 2; ks2++) {
            int slotoff = ((ks2 * 4 + lh) ^ sxor) << 3;
            bf16x8 af[4], bfr[4];
            #pragma unroll
            for (int mi = 0; mi < 4; mi++)
                af[mi] = *(const bf16x8*)(&sA[p][(wm + mi * 16 + lr) * 64 + slotoff]);
            #pragma unroll
            for (int ni = 0; ni < 4; ni++)
                bfr[ni] = *(const bf16x8*)(&sB[p][(wn + ni * 16 + lr) * 64 + slotoff]);
            __builtin_amdgcn_s_setprio(1);
            #pragma unroll
            for (int mi = 0; mi < 4; mi++)
                #pragma unroll
                for (int ni = 0; ni < 4; ni++)
                    acc[mi][ni] = __builtin_amdgcn_mfma_f32_16x16x32_bf16(af[mi], bfr[ni], acc[mi][ni], 0, 0, 0);
            __builtin_amdgcn_s_setprio(0);
        }
        __builtin_amdgcn_sched_barrier(0);
        asm volatile("s_waitcnt lgkmcnt(0)" ::: "memory");
        __builtin_amdgcn_s_barrier();
        p ^= 1;
    }
#undef STAGE
    bf16* pc = part + ((size_t)bz << 20);
    #pragma unroll
    for (int mi = 0; mi < 4; mi++)
        #pragma unroll
        for (int ni = 0; ni < 4; ni++)
            #pragma unroll
            for (int r = 0; r < 4; r++)
                pc[(size_t)(tm + wm + mi * 16 + lh * 4 + r) * 1024 + (tn + wn + ni * 16 + lr)] = (bf16)acc[mi][ni][r];
}

// ---------------- reduce split-K(8, bf16 partials) + bias + BN + ReLU -> bf16 (x1) --------
__global__ void k_reduce1(const bf16* __restrict__ part, const float* __restrict__ bias,
                          const float* __restrict__ gam, const float* __restrict__ bet,
                          const float* __restrict__ mu, const float* __restrict__ var,
                          bf16* __restrict__ x1b) {
    int idx = blockIdx.x * 256 + threadIdx.x;
    int n = idx >> 8;
    int o = (idx & 255) << 2;
    f32x4 v = {};
    #pragma unroll
    for (int s = 0; s < 8; s++) {
        bf16x4 p4 = *(const bf16x4*)(part + ((size_t)s << 20) + (size_t)n * 1024 + o);
        #pragma unroll
        for (int e = 0; e < 4; e++) v[e] += (float)p4[e];
    }
    f32x4 b4 = *(const f32x4*)(bias + o);
    f32x4 g4 = *(const f32x4*)(gam + o);
    f32x4 e4 = *(const f32x4*)(bet + o);
    f32x4 m4 = *(const f32x4*)(mu + o);
    f32x4 v4 = *(const f32x4*)(var + o);
    bf16x4 ov;
    #pragma unroll
    for (int e = 0; e < 4; e++) {
        float sc = g4[e] / sqrtf(v4[e] + 0.001f);
        float y = (v[e] + b4[e] - m4[e]) * sc + e4[e];
        y = fmaxf(y, 0.0f);
        if (n >= NROIS) y = 0.0f;
        ov[e] = (bf16)y;
    }
    *(bf16x4*)(x1b + (size_t)n * 1024 + o) = ov;
}

// ---------------- heads (fused reduce2 + BN2 + ReLU + all three heads) ----------------
__device__ __forceinline__ float wred(float v) {
    #pragma unroll
    for (int off = 32; off; off >>= 1) v += __shfl_xor(v, off);
    return v;
}

__global__ void k_heads(const bf16* __restrict__ part,
                        const float* __restrict__ bias2, const float* __restrict__ g2,
                        const float* __restrict__ be2, const float* __restrict__ m2,
                        const float* __restrict__ v2,
                        const float* __restrict__ wc, const float* __restrict__ bc,
                        const float* __restrict__ wb, const float* __restrict__ bb,
                        const float* __restrict__ wp, const float* __restrict__ bp,
                        float* __restrict__ out) {
    int w = threadIdx.x >> 6, l = threadIdx.x & 63;
    int n = blockIdx.x * 4 + w;   // < 1000 always
    float ac0 = 0.f, ac1 = 0.f, ab[8] = {}, ap[6] = {};
    for (int kk = 0; kk < 16; kk++) {
        int k = kk * 64 + l;
        // x2[n][k] = relu(bn2(sum_s part[s][n][k] + bias2[k]))  (identical math to reduce2)
        float v = 0.f;
        #pragma unroll
        for (int s = 0; s < 8; s++)
            v += (float)part[((size_t)s << 20) + (size_t)n * 1024 + k];
        float sc = g2[k] / sqrtf(v2[k] + 0.001f);
        float xv = fmaxf((v + bias2[k] - m2[k]) * sc + be2[k], 0.0f);
        ac0 += xv * wc[k];
        ac1 += xv * wc[1024 + k];
        #pragma unroll
        for (int o = 0; o < 8; o++) ab[o] += xv * wb[o * 1024 + k];
        #pragma unroll
        for (int o = 0; o < 6; o++) ap[o] += xv * wp[o * 1024 + k];
    }
    ac0 = wred(ac0); ac1 = wred(ac1);
    #pragma unroll
    for (int o = 0; o < 8; o++) ab[o] = wred(ab[o]);
    #pragma unroll
    for (int o = 0; o < 6; o++) ap[o] = wred(ap[o]);
    if (l == 0) {
        float l0 = ac0 + bc[0], l1 = ac1 + bc[1];
        out[n * 2] = l0; out[n * 2 + 1] = l1;
        float m = fmaxf(l0, l1);
        float e0 = expf(l0 - m), e1 = expf(l1 - m);
        float inv = 1.0f / (e0 + e1);
        out[2000 + n * 2] = e0 * inv; out[2000 + n * 2 + 1] = e1 * inv;
        #pragma unroll
        for (int o = 0; o < 8; o++) out[4000 + n * 8 + o] = ab[o] + bb[o];
        #pragma unroll
        for (int o = 0; o < 6; o++) out[12000 + n * 6 + o] = ap[o] + bp[o];
    }
}

extern "C" void kernel_launch(void* const* d_in, const int* in_sizes, int n_in,
                              void* d_out, int out_size, void* d_ws, size_t ws_size,
                              hipStream_t stream) {
    const float* p2      = (const float*)d_in[0];
    const float* p3      = (const float*)d_in[1];
    const float* p4      = (const float*)d_in[2];
    const float* p5      = (const float*)d_in[3];
    const float* rois    = (const float*)d_in[4];
    const float* ranges  = (const float*)d_in[5];
    const float* conv1_w = (const float*)d_in[6];
    const float* conv1_b = (const float*)d_in[7];
    const float* bn1_g   = (const float*)d_in[8];
    const float* bn1_b   = (const float*)d_in[9];
    const float* bn1_m   = (const float*)d_in[10];
    const float* bn1_v   = (const float*)d_in[11];
    const float* conv2_w = (const float*)d_in[12];
    const float* conv2_b = (const float*)d_in[13];
    const float* bn2_g   = (const float*)d_in[14];
    const float* bn2_b   = (const float*)d_in[15];
    const float* bn2_m   = (const float*)d_in[16];
    const float* bn2_v   = (const float*)d_in[17];
    const float* wc      = (const float*)d_in[18];
    const float* bc      = (const float*)d_in[19];
    const float* wb      = (const float*)d_in[20];
    const float* bb      = (const float*)d_in[21];
    const float* wp      = (const float*)d_in[22];
    const float* bp      = (const float*)d_in[23];

    char* ws = (char*)d_ws;
    bf16*  A    = (bf16*)(ws + OFF_A);
    bf16*  Tb   = (bf16*)(ws + OFF_T);
    float* tab  = (float*)(ws + OFF_TAB);
    bf16*  part = (bf16*)(ws + OFF_PART);
    bf16*  W1b  = (bf16*)(ws + OFF_W1);
    bf16*  W2b  = (bf16*)(ws + OFF_W2);
    bf16*  x1b  = (bf16*)(ws + OFF_X1B);
    float* out  = (float*)d_out;

    // prep: transpose (2528) + roi tables (4) + weight convert (16704) = 19236 blocks
    k_prep<<<19236, 256, 0, stream>>>(p2, p3, p4, p5, ranges, Tb, rois, tab,
                                      conv1_w, conv2_w, W1b, W2b);
    k_crop2<<<1024, 256, 0, stream>>>(Tb, tab, out + 18000, A);
    // GEMM1: M=1024 x N=1024 x K=15680, 128x128 tiles, z=8 (245 = 8*30+5), 512 blocks
    k_g128s<1><<<512, 256, 0, stream>>>(A, W1b, part, KDIM, 30, 5);
    k_reduce1<<<1024, 256, 0, stream>>>(part, conv1_b, bn1_g, bn1_b, bn1_m, bn1_v, x1b);
    // GEMM2: K=1024 (16 tiles), z=8 -> 512 blocks
    k_g128s<0><<<dim3(8, 8, 8), 256, 0, stream>>>(x1b, W2b, part, 1024, 2, 0);
    // heads: fused reduce2 + BN2 + ReLU + classifier/bbox/params + softmax
    k_heads<<<250, 256, 0, stream>>>(part, conv2_b, bn2_g, bn2_b, bn2_m, bn2_v,
                                     wc, bc, wb, bb, wp, bp, out);
}